// Round 6
// baseline (233.000 us; speedup 1.0000x reference)
//
#include <hip/hip_runtime.h>
#include <stdint.h>

#define M_DIM 8192
#define N_DIM 4096
#define K_DIM 4096
#define QMAXF 127.0f
#define QDIVF 127.5f

typedef int v4i __attribute__((ext_vector_type(4)));

// ---------------- address-space helpers for global_load_lds ----------------
typedef __attribute__((address_space(3))) void lds_void_t;
typedef __attribute__((address_space(1))) const void glb_void_t;

static __device__ __forceinline__ void load_lds16(const void* g, void* l) {
    __builtin_amdgcn_global_load_lds((glb_void_t*)g, (lds_void_t*)l, 16, 0, 0);
}

// ------- kernel 1: fused per-row absmax + quantize lhs (single pass) -------
__global__ __launch_bounds__(256) void row_quant_kernel(
        const float* __restrict__ lhs, float* __restrict__ sL,
        int8_t* __restrict__ ql) {
    const int row = blockIdx.x;
    const float4* rp = (const float4*)(lhs + (size_t)row * K_DIM);
    const int t = threadIdx.x;
    float4 v[4];
    float m = 0.0f;
#pragma unroll
    for (int i = 0; i < 4; ++i) {
        v[i] = rp[t + i * 256];
        m = fmaxf(m, fmaxf(fmaxf(fabsf(v[i].x), fabsf(v[i].y)),
                           fmaxf(fabsf(v[i].z), fabsf(v[i].w))));
    }
#pragma unroll
    for (int off = 32; off; off >>= 1) m = fmaxf(m, __shfl_down(m, off, 64));
    __shared__ float wmax[4];
    if ((t & 63) == 0) wmax[t >> 6] = m;
    __syncthreads();
    const float mm = fmaxf(fmaxf(wmax[0], wmax[1]), fmaxf(wmax[2], wmax[3]));
    float s = mm / QDIVF;
    s = (s == 0.0f) ? 1.0f : s;
    if (t == 0) sL[row] = s;
    unsigned* qo = (unsigned*)ql + (size_t)row * 1024;
#pragma unroll
    for (int i = 0; i < 4; ++i) {
        int q0 = (int)fminf(fmaxf(rintf(v[i].x / s), -QMAXF), QMAXF);
        int q1 = (int)fminf(fmaxf(rintf(v[i].y / s), -QMAXF), QMAXF);
        int q2 = (int)fminf(fmaxf(rintf(v[i].z / s), -QMAXF), QMAXF);
        int q3 = (int)fminf(fmaxf(rintf(v[i].w / s), -QMAXF), QMAXF);
        qo[t + i * 256] = (q0 & 255) | ((q1 & 255) << 8) | ((q2 & 255) << 16)
                        | ((unsigned)(q3 & 255) << 24);
    }
}

// ---------------- kernel 2a: per-col absmax partial (rhs) ----------------
__global__ __launch_bounds__(256) void col_absmax_kernel(
        const float* __restrict__ rhs, unsigned* __restrict__ bits) {
    const int col = blockIdx.x * 256 + threadIdx.x;
    const int r0 = blockIdx.y * 64;
    float m = 0.0f;
#pragma unroll 4
    for (int r = 0; r < 64; ++r)
        m = fmaxf(m, fabsf(rhs[(size_t)(r0 + r) * N_DIM + col]));
    atomicMax(&bits[col], __float_as_uint(m));
}

// ---------------- kernel 2b: bits -> scale ----------------
__global__ __launch_bounds__(256) void col_scale_kernel(
        const unsigned* __restrict__ bits, float* __restrict__ sR) {
    const int c = blockIdx.x * 256 + threadIdx.x;
    float s = __uint_as_float(bits[c]) / QDIVF;
    sR[c] = (s == 0.0f) ? 1.0f : s;
}

// -------- kernel 4: quantize + transpose rhs -> q_rT [N][K] int8 --------
__global__ __launch_bounds__(256) void quant_rhs_t_kernel(
        const float* __restrict__ rhs, const float* __restrict__ sR,
        int8_t* __restrict__ qbT) {
    __shared__ __align__(16) int8_t lt[64][80];
    const int n0 = blockIdx.x * 64;
    const int k0 = blockIdx.y * 64;
    const int t = threadIdx.x;
    const int nloc = t & 63;
    const int kq = (t >> 6) * 16;
    const float s = sR[n0 + nloc];
#pragma unroll
    for (int i = 0; i < 4; ++i) {
        unsigned pack = 0;
#pragma unroll
        for (int j = 0; j < 4; ++j) {
            int kk = kq + i * 4 + j;
            float x = rhs[(size_t)(k0 + kk) * N_DIM + n0 + nloc];
            int q = (int)fminf(fmaxf(rintf(x / s), -QMAXF), QMAXF);
            pack |= (unsigned)(q & 255) << (8 * j);
        }
        *(unsigned*)&lt[nloc][kq + i * 4] = pack;
    }
    __syncthreads();
    const int nn = t >> 2, ch = t & 3;
    v4i val = *(const v4i*)&lt[nn][ch * 16];
    *(v4i*)&qbT[(size_t)(n0 + nn) * K_DIM + k0 + ch * 16] = val;
}

// ===== kernel 5: int8 GEMM, 256x128 tile, BK=64, ring-2, 2 blocks/CU =====
// Goal: break the measured pipe-serialization (MFMA 1242 + LDS 1000 + VALU 470
// ≈ 2790 cy/tile, all sequential at 1 block/CU). 48 KB LDS + VGPR<=128
// (launch_bounds 512,4) -> 2 independent blocks/CU whose pipes cross-fill.
// 8 waves (4M x 2N), per-wave 64x64 = 4x4 frags of mfma_i32_16x16x64_i8.
// Swizzle (R5-validated, 64B rows): phys_chunk = logical ^ ((row>>1)&3),
// applied on BOTH stage-source and ds_read. One barrier per tile.

#define BAR() do { asm volatile("" ::: "memory");          \
                   __builtin_amdgcn_s_barrier();           \
                   asm volatile("" ::: "memory"); } while (0)

#define VMCNT(N) asm volatile("s_waitcnt vmcnt(%0)" :: "n"(N) : "memory")

#define RD_A(BUF, MM) (*(const v4i*)(lds + (BUF) * 16384 + aoff[MM]))
#define RD_B(BUF, NN) (*(const v4i*)(lds + 32768 + (BUF) * 8192 + boff[NN]))

// TILE body: BUF compile-time. S: stage tile KT+1 into BUF^1 (3 loads) and
// advance K-pointers (incremental addressing: ~6 VALU instead of fresh mads).
#define TILE(BUF, S) do {                                                       \
    if (S) {                                                                    \
        load_lds16(pA,                      lds + ((BUF) ^ 1) * 16384 + sdst);  \
        load_lds16(pA + (size_t)128 * K_DIM,                                    \
                   lds + ((BUF) ^ 1) * 16384 + 8192 + sdst);                    \
        load_lds16(pB, lds + 32768 + ((BUF) ^ 1) * 8192 + sdst);                \
        pA += 64; pB += 64;                                                     \
    }                                                                           \
    _Pragma("unroll") for (int mm = 0; mm < 4; ++mm) af[mm] = RD_A(BUF, mm);    \
    _Pragma("unroll") for (int nn = 0; nn < 4; ++nn) bf[nn] = RD_B(BUF, nn);    \
    __builtin_amdgcn_s_setprio(1);                                              \
    _Pragma("unroll") for (int mm = 0; mm < 4; ++mm)                            \
    _Pragma("unroll") for (int nn = 0; nn < 4; ++nn)                            \
        acc[mm][nn] = __builtin_amdgcn_mfma_i32_16x16x64_i8(                    \
            af[mm], bf[nn], acc[mm][nn], 0, 0, 0);                              \
    __builtin_amdgcn_s_setprio(0);                                              \
    VMCNT(0);                                                                   \
    BAR();                                                                      \
} while (0)

__global__ __launch_bounds__(512, 4) void gemm_i8_kernel(
        const int8_t* __restrict__ qa, const int8_t* __restrict__ qbT,
        const float* __restrict__ sL, const float* __restrict__ sR,
        float* __restrict__ out) {
    __shared__ __align__(16) int8_t lds[49152];   // A 2x16KB @0, B 2x8KB @32768

    const int t = threadIdx.x;
    const int wave = t >> 6;
    const int lane = t & 63;

    // XCD partition: 1024 blocks; xcd gets an 8M x 16N chunk (bijective).
    const int bid = blockIdx.x;
    const int xcd = bid & 7;
    const int idx = bid >> 3;                 // 0..127
    const int mt = (xcd >> 1) * 8 + (idx & 7);   // 0..31
    const int nt = (xcd & 1) * 16 + (idx >> 3);  // 0..31
    const int brow = mt * 256;
    const int bcol = nt * 128;

    const int wm = (wave >> 1) * 64;     // 4 M-groups of 64 rows
    const int wn = (wave & 1) * 64;      // 2 N-groups of 64 cols

    // fragment read byte-offsets (swizzled); rows are 64B (R5-validated)
    int aoff[4], boff[4];
#pragma unroll
    for (int m = 0; m < 4; ++m) {
        int row = wm + m * 16 + (lane & 15);
        aoff[m] = row * 64 + (((lane >> 4) ^ ((row >> 1) & 3)) * 16);
    }
#pragma unroll
    for (int n = 0; n < 4; ++n) {
        int row = wn + n * 16 + (lane & 15);
        boff[n] = row * 64 + (((lane >> 4) ^ ((row >> 1) & 3)) * 16);
    }

    v4i acc[4][4];
#pragma unroll
    for (int m = 0; m < 4; ++m)
#pragma unroll
        for (int n = 0; n < 4; ++n) acc[m][n] = (v4i){0, 0, 0, 0};

    // staging: thread t covers bytes [t*16, t*16+16) of an 8KB chunk
    // (128 rows x 64B). Source chunk pre-swizzled so LDS is linear.
    const int srow = t >> 2;                                  // 0..127
    const int lc = (t & 3) ^ ((srow >> 3) & 3) ^ ((srow & 4) ? 0 : 0); // see below
    // NOTE: row>>1 & 3 uses bits 1..2 of row; row = srow -> ((srow>>1)&3)
    const int lcA = (t & 3) ^ ((srow >> 1) & 3);
    (void)lc;
    const int8_t* gA0 = qa  + (size_t)(brow + srow) * K_DIM + lcA * 16;
    const int8_t* gB0 = qbT + (size_t)(bcol + srow) * K_DIM + lcA * 16;
    const int sdst = t * 16;

    const int8_t* pA = gA0 + 64;   // next-staged tile's K offset (tile 1)
    const int8_t* pB = gB0 + 64;

    v4i af[4], bf[4];

    // prologue: stage tile 0 -> buf0; drain; publish
    load_lds16(gA0,                        lds + sdst);
    load_lds16(gA0 + (size_t)128 * K_DIM,  lds + 8192 + sdst);
    load_lds16(gB0,                        lds + 32768 + sdst);
    VMCNT(0);
    BAR();

    for (int kt = 0; kt < 62; kt += 2) {
        TILE(0, 1);
        TILE(1, 1);
    }
    TILE(0, 1);   // tile 62, stages tile 63
    TILE(1, 0);   // tile 63

    // Epilogue (validated): 16x16 C/D: col = lane&15, row = (lane>>4)*4 + reg
    const int r4 = (lane >> 4) * 4;
    const int cc = lane & 15;
#pragma unroll
    for (int m = 0; m < 4; ++m) {
        const int grow0 = brow + wm + m * 16 + r4;
        const float s0 = sL[grow0 + 0];
        const float s1 = sL[grow0 + 1];
        const float s2 = sL[grow0 + 2];
        const float s3 = sL[grow0 + 3];
#pragma unroll
        for (int n = 0; n < 4; ++n) {
            const int gcol = bcol + wn + n * 16 + cc;
            const float sc = sR[gcol];
            float* o = out + (size_t)grow0 * N_DIM + gcol;
            o[0 * N_DIM] = (float)acc[m][n][0] * s0 * sc;
            o[1 * N_DIM] = (float)acc[m][n][1] * s1 * sc;
            o[2 * N_DIM] = (float)acc[m][n][2] * s2 * sc;
            o[3 * N_DIM] = (float)acc[m][n][3] * s3 * sc;
        }
    }
}

// ---------------- launch ----------------
extern "C" void kernel_launch(void* const* d_in, const int* in_sizes, int n_in,
                              void* d_out, int out_size, void* d_ws, size_t ws_size,
                              hipStream_t stream) {
    const float* lhs = (const float*)d_in[0];
    const float* rhs = (const float*)d_in[1];
    float* out = (float*)d_out;

    uint8_t* ws = (uint8_t*)d_ws;
    int8_t* ql    = (int8_t*)ws;                               // 33,554,432 B
    int8_t* qbT   = (int8_t*)(ws + 33554432);                  // 16,777,216 B
    float* sL     = (float*)(ws + 50331648);                   // 32,768 B
    float* sR     = (float*)(ws + 50331648 + 32768);           // 16,384 B
    unsigned* bits = (unsigned*)(ws + 50331648 + 32768 + 16384); // 16,384 B

    hipMemsetAsync(bits, 0, N_DIM * sizeof(unsigned), stream);

    row_quant_kernel<<<M_DIM, 256, 0, stream>>>(lhs, sL, ql);
    col_absmax_kernel<<<dim3(N_DIM / 256, K_DIM / 64), 256, 0, stream>>>(rhs, bits);
    col_scale_kernel<<<N_DIM / 256, 256, 0, stream>>>(bits, sR);
    quant_rhs_t_kernel<<<dim3(N_DIM / 64, K_DIM / 64), 256, 0, stream>>>(rhs, sR, qbT);
    gemm_i8_kernel<<<dim3((M_DIM / 256) * (N_DIM / 128)), 512, 0, stream>>>(
        ql, qbT, sL, sR, out);
}

// Round 7
// 219.177 us; speedup vs baseline: 1.0631x; 1.0631x over previous
//
#include <hip/hip_runtime.h>
#include <stdint.h>

#define M_DIM 8192
#define N_DIM 4096
#define K_DIM 4096
#define QMAXF 127.0f
#define QDIVF 127.5f

typedef int v4i  __attribute__((ext_vector_type(4)));
typedef int v16i __attribute__((ext_vector_type(16)));

// ---------------- address-space helpers for global_load_lds ----------------
typedef __attribute__((address_space(3))) void lds_void_t;
typedef __attribute__((address_space(1))) const void glb_void_t;

static __device__ __forceinline__ void load_lds16(const void* g, void* l) {
    __builtin_amdgcn_global_load_lds((glb_void_t*)g, (lds_void_t*)l, 16, 0, 0);
}

// ---- kernel 1: fused prep pass 1: [row absmax+quant lhs] ∥ [col absmax rhs] ----
// blocks 0..8191: one lhs row each (read once, quantize in-reg).
// blocks 8192..9215: rhs col-absmax partials (atomicMax on abs bits).
__global__ __launch_bounds__(256) void prep1_kernel(
        const float* __restrict__ lhs, const float* __restrict__ rhs,
        float* __restrict__ sL, unsigned* __restrict__ bits,
        int8_t* __restrict__ ql) {
    const int t = threadIdx.x;
    if (blockIdx.x < M_DIM) {
        const int row = blockIdx.x;
        const float4* rp = (const float4*)(lhs + (size_t)row * K_DIM);
        float4 v[4];
        float m = 0.0f;
#pragma unroll
        for (int i = 0; i < 4; ++i) {
            v[i] = rp[t + i * 256];
            m = fmaxf(m, fmaxf(fmaxf(fabsf(v[i].x), fabsf(v[i].y)),
                               fmaxf(fabsf(v[i].z), fabsf(v[i].w))));
        }
#pragma unroll
        for (int off = 32; off; off >>= 1) m = fmaxf(m, __shfl_down(m, off, 64));
        __shared__ float wmax[4];
        if ((t & 63) == 0) wmax[t >> 6] = m;
        __syncthreads();
        const float mm = fmaxf(fmaxf(wmax[0], wmax[1]), fmaxf(wmax[2], wmax[3]));
        float s = mm / QDIVF;
        s = (s == 0.0f) ? 1.0f : s;
        if (t == 0) sL[row] = s;
        unsigned* qo = (unsigned*)ql + (size_t)row * 1024;
#pragma unroll
        for (int i = 0; i < 4; ++i) {
            int q0 = (int)fminf(fmaxf(rintf(v[i].x / s), -QMAXF), QMAXF);
            int q1 = (int)fminf(fmaxf(rintf(v[i].y / s), -QMAXF), QMAXF);
            int q2 = (int)fminf(fmaxf(rintf(v[i].z / s), -QMAXF), QMAXF);
            int q3 = (int)fminf(fmaxf(rintf(v[i].w / s), -QMAXF), QMAXF);
            qo[t + i * 256] = (q0 & 255) | ((q1 & 255) << 8) | ((q2 & 255) << 16)
                            | ((unsigned)(q3 & 255) << 24);
        }
    } else {
        const int cb = blockIdx.x - M_DIM;     // 0..1023
        const int col = (cb & 15) * 256 + t;
        const int r0 = (cb >> 4) * 64;
        float m = 0.0f;
#pragma unroll 4
        for (int r = 0; r < 64; ++r)
            m = fmaxf(m, fabsf(rhs[(size_t)(r0 + r) * N_DIM + col]));
        atomicMax(&bits[col], __float_as_uint(m));   // abs >= 0: bit order == float order
    }
}

// -- kernel 2: quantize + transpose rhs -> q_rT [N][K]; also materialize sR --
__global__ __launch_bounds__(256) void quant_rhs_t_kernel(
        const float* __restrict__ rhs, const unsigned* __restrict__ bits,
        float* __restrict__ sR, int8_t* __restrict__ qbT) {
    __shared__ __align__(16) int8_t lt[64][80];
    const int n0 = blockIdx.x * 64;
    const int k0 = blockIdx.y * 64;
    const int t = threadIdx.x;
    const int nloc = t & 63;
    const int kq = (t >> 6) * 16;
    float s = __uint_as_float(bits[n0 + nloc]) / QDIVF;
    s = (s == 0.0f) ? 1.0f : s;
    if (blockIdx.y == 0 && t < 64) sR[n0 + t] = (__uint_as_float(bits[n0 + t]) / QDIVF == 0.0f)
                                               ? 1.0f : __uint_as_float(bits[n0 + t]) / QDIVF;
#pragma unroll
    for (int i = 0; i < 4; ++i) {
        unsigned pack = 0;
#pragma unroll
        for (int j = 0; j < 4; ++j) {
            int kk = kq + i * 4 + j;
            float x = rhs[(size_t)(k0 + kk) * N_DIM + n0 + nloc];
            int q = (int)fminf(fmaxf(rintf(x / s), -QMAXF), QMAXF);
            pack |= (unsigned)(q & 255) << (8 * j);
        }
        *(unsigned*)&lt[nloc][kq + i * 4] = pack;
    }
    __syncthreads();
    const int nn = t >> 2, ch = t & 3;
    v4i val = *(const v4i*)&lt[nn][ch * 16];
    *(v4i*)&qbT[(size_t)(n0 + nn) * K_DIM + k0 + ch * 16] = val;
}

// ====== kernel 3: int8 GEMM, 256x256 tile, BK=64, ring-4, 1 barrier/tile ======
// mfma_i32_32x32x32_i8 (half the instr count of 16x16x64, 4404 vs 3944 TOPS).
// Schedule = R5-validated: at the barrier ending tile KT, tiles <= KT+2 are
// landed for ALL waves (VMCNT(4) before barrier drains KT+2). Tile KT reads:
// ks1 operands of KT at tile top; ks0 operands of KT+1 between clusters.
// 8 waves (4M x 2N), per-wave 64x128 = 2mf x 4nf frags of 32x32.
// 16B-chunk swizzle phys = c ^ ((row>>1)&3) on BOTH stage-source and ds_read.

#define BAR() do { asm volatile("" ::: "memory");          \
                   __builtin_amdgcn_s_barrier();           \
                   asm volatile("" ::: "memory"); } while (0)

#define VMCNT(N) asm volatile("s_waitcnt vmcnt(%0)" :: "n"(N) : "memory")

#define STAGE_A(h, kt, bq) \
    load_lds16(gA0 + (size_t)((h) * 128) * K_DIM + (size_t)(kt) * 64, \
               lds + (bq) * 16384 + (h) * 8192 + sdst)
#define STAGE_B(h, kt, bq) \
    load_lds16(gB0 + (size_t)((h) * 128) * K_DIM + (size_t)(kt) * 64, \
               lds + 65536 + (bq) * 16384 + (h) * 8192 + sdst)

#define RD_A(BUF, MF, KS) (*(const v4i*)(lds + (BUF) * 16384 + aoff[MF][KS]))
#define RD_B(BUF, NF, KS) (*(const v4i*)(lds + (BUF) * 16384 + boff[NF][KS]))

// TILE: BUF = KT & 3, P = KT & 1 (compile-time). S: stage KT+3. RDN: read KT+1 ks0.
#define TILE(KT, BUF, P, S, VM, RDN) do {                                       \
    _Pragma("unroll") for (int mf = 0; mf < 2; ++mf) a1[mf] = RD_A(BUF, mf, 1); \
    _Pragma("unroll") for (int nf = 0; nf < 4; ++nf) b1[nf] = RD_B(BUF, nf, 1); \
    if (S) { STAGE_A(0, (KT) + 3, ((BUF) + 3) & 3);                             \
             STAGE_A(1, (KT) + 3, ((BUF) + 3) & 3);                             \
             STAGE_B(0, (KT) + 3, ((BUF) + 3) & 3);                             \
             STAGE_B(1, (KT) + 3, ((BUF) + 3) & 3); }                           \
    __builtin_amdgcn_s_setprio(1);                                              \
    _Pragma("unroll") for (int mf = 0; mf < 2; ++mf)                            \
    _Pragma("unroll") for (int nf = 0; nf < 4; ++nf)                            \
        acc[mf][nf] = __builtin_amdgcn_mfma_i32_32x32x32_i8(                    \
            a0[P][mf], b0[P][nf], acc[mf][nf], 0, 0, 0);                        \
    __builtin_amdgcn_s_setprio(0);                                              \
    if (RDN) {                                                                  \
        _Pragma("unroll") for (int mf = 0; mf < 2; ++mf)                        \
            a0[(P) ^ 1][mf] = RD_A(((BUF) + 1) & 3, mf, 0);                     \
        _Pragma("unroll") for (int nf = 0; nf < 4; ++nf)                        \
            b0[(P) ^ 1][nf] = RD_B(((BUF) + 1) & 3, nf, 0);                     \
    }                                                                           \
    __builtin_amdgcn_s_setprio(1);                                              \
    _Pragma("unroll") for (int mf = 0; mf < 2; ++mf)                            \
    _Pragma("unroll") for (int nf = 0; nf < 4; ++nf)                            \
        acc[mf][nf] = __builtin_amdgcn_mfma_i32_32x32x32_i8(                    \
            a1[mf], b1[nf], acc[mf][nf], 0, 0, 0);                              \
    __builtin_amdgcn_s_setprio(0);                                              \
    VMCNT(VM);                                                                  \
    BAR();                                                                      \
} while (0)

__global__ __launch_bounds__(512, 2) void gemm_i8_kernel(
        const int8_t* __restrict__ qa, const int8_t* __restrict__ qbT,
        const float* __restrict__ sL, const float* __restrict__ sR,
        float* __restrict__ out) {
    __shared__ __align__(16) int8_t lds[131072];

    const int t = threadIdx.x;
    const int wave = t >> 6;
    const int lane = t & 63;

    // 2D XCD partition (R6-validated: FETCH 274->100MB): each XCD owns an
    // 8mt x 8nt chunk. 512 blocks, bijective.
    const int bid = blockIdx.x;
    const int xcd = bid & 7;
    const int idx = bid >> 3;                    // 0..63
    const int mt = (xcd >> 1) * 8 + (idx & 7);   // 0..31
    const int nt = (xcd & 1) * 8 + (idx >> 3);   // 0..15
    const int brow = mt * 256;
    const int bcol = nt * 256;

    const int wm = (wave >> 1) * 64;     // 4 M-groups of 64 rows
    const int wn = (wave & 1) * 128;     // 2 N-groups of 128 cols

    // frag read offsets: row = wgroup + f*32 + (lane&31); 16B chunk
    // c = ks*2 + (lane>>5); phys = c ^ ((row>>1)&3). Rows are 64B.
    int aoff[2][2], boff[4][2];
#pragma unroll
    for (int mf = 0; mf < 2; ++mf) {
        int row = wm + mf * 32 + (lane & 31);
#pragma unroll
        for (int ks = 0; ks < 2; ++ks)
            aoff[mf][ks] = row * 64 + (((ks * 2 + (lane >> 5)) ^ ((row >> 1) & 3)) * 16);
    }
#pragma unroll
    for (int nf = 0; nf < 4; ++nf) {
        int row = wn + nf * 32 + (lane & 31);
#pragma unroll
        for (int ks = 0; ks < 2; ++ks)
            boff[nf][ks] = 65536 + row * 64 + (((ks * 2 + (lane >> 5)) ^ ((row >> 1) & 3)) * 16);
    }

    v16i acc[2][4];
#pragma unroll
    for (int mf = 0; mf < 2; ++mf)
#pragma unroll
        for (int nf = 0; nf < 4; ++nf) acc[mf][nf] = (v16i)(0);

    // staging: thread t covers bytes [t*16, t*16+16) of an 8KB half-tile;
    // source chunk pre-swizzled so linear LDS holds the swizzled layout.
    const int srow = t >> 2;                                  // 0..127
    const int lcA = (t & 3) ^ ((srow >> 1) & 3);
    const int8_t* gA0 = qa  + (size_t)(brow + srow) * K_DIM + lcA * 16;
    const int8_t* gB0 = qbT + (size_t)(bcol + srow) * K_DIM + lcA * 16;
    const int sdst = t * 16;

    v4i a0[2][2], b0[2][4], a1[2], b1[4];

    // prologue: stage tiles 0,1,2 (tile-monotone); drain T0,T1 for ALL waves
    // (VMCNT then BARRIER) BEFORE any LDS read -> no cross-wave race.
    STAGE_A(0, 0, 0); STAGE_A(1, 0, 0); STAGE_B(0, 0, 0); STAGE_B(1, 0, 0);
    STAGE_A(0, 1, 1); STAGE_A(1, 1, 1); STAGE_B(0, 1, 1); STAGE_B(1, 1, 1);
    STAGE_A(0, 2, 2); STAGE_A(1, 2, 2); STAGE_B(0, 2, 2); STAGE_B(1, 2, 2);
    VMCNT(4);
    BAR();
#pragma unroll
    for (int mf = 0; mf < 2; ++mf) a0[0][mf] = RD_A(0, mf, 0);
#pragma unroll
    for (int nf = 0; nf < 4; ++nf) b0[0][nf] = RD_B(0, nf, 0);

    for (int kt = 0; kt < 60; kt += 4) {
        TILE(kt + 0, 0, 0, 1, 4, 1);
        TILE(kt + 1, 1, 1, 1, 4, 1);
        TILE(kt + 2, 2, 0, 1, 4, 1);
        TILE(kt + 3, 3, 1, 1, 4, 1);
    }
    TILE(60, 0, 0, 1, 4, 1);   // stages T63; drains T62
    TILE(61, 1, 1, 0, 0, 1);   // drains T63 before barrier
    TILE(62, 2, 0, 0, 0, 1);
    TILE(63, 3, 1, 0, 0, 0);

    // Epilogue: 32x32 C/D (guide-verified m74/m101):
    // col = lane&31, row = (reg&3) + 8*(reg>>2) + 4*(lane>>5)
    const int cc = lane & 31;
    const int lh = (lane >> 5) * 4;
#pragma unroll
    for (int mf = 0; mf < 2; ++mf) {
        const int rbase = brow + wm + mf * 32 + lh;
        float slv[16];
#pragma unroll
        for (int q = 0; q < 4; ++q)
#pragma unroll
            for (int j = 0; j < 4; ++j)
                slv[q * 4 + j] = sL[rbase + q * 8 + j];
#pragma unroll
        for (int nf = 0; nf < 4; ++nf) {
            const int gcol = bcol + wn + nf * 32 + cc;
            const float sc = sR[gcol];
#pragma unroll
            for (int q = 0; q < 4; ++q)
#pragma unroll
                for (int j = 0; j < 4; ++j) {
                    const int grow = rbase + q * 8 + j;
                    out[(size_t)grow * N_DIM + gcol] =
                        (float)acc[mf][nf][q * 4 + j] * slv[q * 4 + j] * sc;
                }
        }
    }
}

// ---------------- launch ----------------
extern "C" void kernel_launch(void* const* d_in, const int* in_sizes, int n_in,
                              void* d_out, int out_size, void* d_ws, size_t ws_size,
                              hipStream_t stream) {
    const float* lhs = (const float*)d_in[0];
    const float* rhs = (const float*)d_in[1];
    float* out = (float*)d_out;

    uint8_t* ws = (uint8_t*)d_ws;
    int8_t* ql    = (int8_t*)ws;                               // 33,554,432 B
    int8_t* qbT   = (int8_t*)(ws + 33554432);                  // 16,777,216 B
    float* sL     = (float*)(ws + 50331648);                   // 32,768 B
    float* sR     = (float*)(ws + 50331648 + 32768);           // 16,384 B
    unsigned* bits = (unsigned*)(ws + 50331648 + 32768 + 16384); // 16,384 B

    hipMemsetAsync(bits, 0, N_DIM * sizeof(unsigned), stream);

    prep1_kernel<<<M_DIM + 1024, 256, 0, stream>>>(lhs, rhs, sL, bits, ql);
    quant_rhs_t_kernel<<<dim3(N_DIM / 64, K_DIM / 64), 256, 0, stream>>>(
        rhs, bits, sR, qbT);
    gemm_i8_kernel<<<dim3((M_DIM / 256) * (N_DIM / 256)), 512, 0, stream>>>(
        ql, qbT, sL, sR, out);
}